// Round 1
// baseline (249.797 us; speedup 1.0000x reference)
//
#include <hip/hip_runtime.h>
#include <stdint.h>

#define DM   1024
#define SEQ  2048
#define NH   16
#define HD   64

typedef _Float16 f16;
typedef f16   half8 __attribute__((ext_vector_type(8)));
typedef float f32x4 __attribute__((ext_vector_type(4)));
typedef unsigned int   u32;
typedef unsigned short u16;

__device__ __forceinline__ void gl_lds16(const void* g, void* l) {
  __builtin_amdgcn_global_load_lds(
      reinterpret_cast<__attribute__((address_space(1))) u32*>(reinterpret_cast<uintptr_t>(g)),
      reinterpret_cast<__attribute__((address_space(3))) u32*>(reinterpret_cast<uintptr_t>(l)),
      16, 0, 0);
}

// ---------------- cast f32 -> f16, 8 elems/thread ----------------
__global__ __launch_bounds__(256) void cast_f2h(const float* __restrict__ s,
                                                f16* __restrict__ d, int n8) {
  int i = blockIdx.x * 256 + threadIdx.x;
  if (i >= n8) return;
  const float4* s4 = reinterpret_cast<const float4*>(s);
  float4 a = s4[2 * (size_t)i];
  float4 b = s4[2 * (size_t)i + 1];
  half8 o;
  o[0] = (f16)a.x; o[1] = (f16)a.y; o[2] = (f16)a.z; o[3] = (f16)a.w;
  o[4] = (f16)b.x; o[5] = (f16)b.y; o[6] = (f16)b.z; o[7] = (f16)b.w;
  *reinterpret_cast<half8*>(d + 8 * (size_t)i) = o;
}

// ---------------- GEMM: C[M,N] = A[M,K] @ W[N,K]^T + bias, K=N=1024 ----------
// m97 structure: 128x128 tile, BK=32, 4 waves (2x2), 4x4 16x16x32 frags/wave.
template <int F16OUT>
__global__ __launch_bounds__(256) void gemm_bt(
    const f16* __restrict__ A0, const f16* __restrict__ A1, const f16* __restrict__ A2,
    const f16* __restrict__ W0, const f16* __restrict__ W1, const f16* __restrict__ W2,
    const float* __restrict__ b0, const float* __restrict__ b1, const float* __restrict__ b2,
    void* __restrict__ C0, void* __restrict__ C1, void* __restrict__ C2) {
  int z = blockIdx.z;
  const f16* A = (z == 0) ? A0 : (z == 1) ? A1 : A2;
  const f16* W = (z == 0) ? W0 : (z == 1) ? W1 : W2;
  const float* bias = (z == 0) ? b0 : (z == 1) ? b1 : b2;
  void* C = (z == 0) ? C0 : (z == 1) ? C1 : C2;

  __shared__ f16 As[128 * 32];
  __shared__ f16 Ws[128 * 32];

  int t = threadIdx.x;
  int w = t >> 6, lane = t & 63, lr = lane & 15, lk = lane >> 4;
  int m0 = blockIdx.y * 128, n0 = blockIdx.x * 128;
  int wr = (w >> 1) * 64, wc = (w & 1) * 64;

  int srow = t >> 2, scol = (t & 3) * 8;
  const f16* ga = A + (size_t)(m0 + srow) * DM + scol;
  const f16* gw = W + (size_t)(n0 + srow) * DM + scol;

  f32x4 zero4 = {0.f, 0.f, 0.f, 0.f};
  f32x4 acc[4][4];
#pragma unroll
  for (int mb = 0; mb < 4; ++mb)
#pragma unroll
    for (int nb = 0; nb < 4; ++nb) acc[mb][nb] = zero4;

  for (int k0 = 0; k0 < DM; k0 += 32) {
    gl_lds16(ga + k0,                  As + t * 8);
    gl_lds16(ga + k0 + (size_t)64 * DM, As + 2048 + t * 8);
    gl_lds16(gw + k0,                  Ws + t * 8);
    gl_lds16(gw + k0 + (size_t)64 * DM, Ws + 2048 + t * 8);
    __syncthreads();
    half8 af[4], wf[4];
#pragma unroll
    for (int mb = 0; mb < 4; ++mb)
      af[mb] = *reinterpret_cast<const half8*>(&As[(wr + mb * 16 + lr) * 32 + lk * 8]);
#pragma unroll
    for (int nb = 0; nb < 4; ++nb)
      wf[nb] = *reinterpret_cast<const half8*>(&Ws[(wc + nb * 16 + lr) * 32 + lk * 8]);
#pragma unroll
    for (int mb = 0; mb < 4; ++mb)
#pragma unroll
      for (int nb = 0; nb < 4; ++nb)
        acc[mb][nb] = __builtin_amdgcn_mfma_f32_16x16x32_f16(af[mb], wf[nb], acc[mb][nb], 0, 0, 0);
    __syncthreads();
  }

  float bv[4];
#pragma unroll
  for (int nb = 0; nb < 4; ++nb) bv[nb] = bias[n0 + wc + nb * 16 + lr];
#pragma unroll
  for (int mb = 0; mb < 4; ++mb)
#pragma unroll
    for (int nb = 0; nb < 4; ++nb)
#pragma unroll
      for (int j = 0; j < 4; ++j) {
        int r = m0 + wr + mb * 16 + lk * 4 + j;
        int c = n0 + wc + nb * 16 + lr;
        float v = acc[mb][nb][j] + bv[nb];
        if (F16OUT)
          ((f16*)C)[(size_t)r * DM + c] = (f16)v;
        else
          ((float*)C)[(size_t)r * DM + c] = v;
      }
}

// ---------------- flash attention fwd ----------------
// grid (16 qtiles, 32 b*h), 256 thr. QBLK=128 (32 rows/wave), KVBLK=64.
__global__ __launch_bounds__(256) void attn_fwd(const f16* __restrict__ Qg,
                                                const f16* __restrict__ Kg,
                                                const f16* __restrict__ Vg,
                                                f16* __restrict__ Og) {
  int qt = blockIdx.x;
  int bh = blockIdx.y;
  int b = bh >> 4, h = bh & 15;
  size_t base = (size_t)b * SEQ * DM + (size_t)h * HD;
  const f16* Qp = Qg + base + (size_t)(qt * 128) * DM;
  const f16* Kp = Kg + base;
  const f16* Vp = Vg + base;
  f16* Op = Og + base + (size_t)(qt * 128) * DM;

  __shared__ f16 Plds[128 * 64];  // Q staging, then per-wave P
  __shared__ f16 Klds[64 * 64];   // [kv][d], XOR-swizzled rows
  __shared__ f16 Vlds[64 * 64];   // [d][kv], XOR-swizzled

  int t = threadIdx.x;
  int w = t >> 6, lane = t & 63, lr = lane & 15, lk = lane >> 4;
  int rr = t >> 3, cb = t & 7;

  // stage Q (swizzled source -> linear LDS)
#pragma unroll
  for (int i = 0; i < 4; ++i) {
    int row = i * 32 + rr;
    int gcb = cb ^ (row & 7);
    gl_lds16(Qp + (size_t)row * DM + gcb * 8, Plds + i * 2048 + t * 8);
  }
  __syncthreads();
  half8 qf[2][2];
#pragma unroll
  for (int mb = 0; mb < 2; ++mb)
#pragma unroll
    for (int kk = 0; kk < 2; ++kk) {
      int row = w * 32 + mb * 16 + lr;
      int byo = (kk * 64 + lk * 16) ^ ((row & 7) << 4);
      qf[mb][kk] = *reinterpret_cast<const half8*>(
          reinterpret_cast<const char*>(&Plds[row * 64]) + byo);
    }
  __syncthreads();  // all Q reads done before Plds reused as P

  f32x4 zero4 = {0.f, 0.f, 0.f, 0.f};
  f32x4 o[2][4];
  float m_r[2][4], l_r[2][4];
#pragma unroll
  for (int mb = 0; mb < 2; ++mb)
#pragma unroll
    for (int rg = 0; rg < 4; ++rg) {
      m_r[mb][rg] = -1e30f;
      l_r[mb][rg] = 0.f;
#pragma unroll
      for (int nd = 0; nd < 4; ++nd) o[mb][nd] = zero4;
    }

  for (int kt = 0; kt < SEQ / 64; ++kt) {
    const f16* Kt = Kp + (size_t)(kt * 64) * DM;
    const f16* Vt = Vp + (size_t)(kt * 64) * DM;
    // stage K (swizzled source -> linear LDS)
#pragma unroll
    for (int i = 0; i < 2; ++i) {
      int row = i * 32 + rr;
      int gcb = cb ^ (row & 7);
      gl_lds16(Kt + (size_t)row * DM + gcb * 8, Klds + i * 2048 + t * 8);
    }
    // stage V transposed: [d][kv], swizzle f(d)=(d&7)^((d>>3)&7)
#pragma unroll
    for (int i = 0; i < 2; ++i) {
      int kv = i * 32 + rr;
      int d0 = cb * 8;
      half8 vv = *reinterpret_cast<const half8*>(Vt + (size_t)kv * DM + d0);
#pragma unroll
      for (int j = 0; j < 8; ++j) {
        int d = d0 + j;
        int f = (d & 7) ^ ((d >> 3) & 7);
        int byo = (kv * 2) ^ (f << 4);
        *reinterpret_cast<f16*>(reinterpret_cast<char*>(&Vlds[d * 64]) + byo) = vv[j];
      }
    }
    __syncthreads();

    // S = Q @ K^T  (per wave: 32 q rows x 64 kv)
    f32x4 s[2][4];
#pragma unroll
    for (int mb = 0; mb < 2; ++mb)
#pragma unroll
      for (int nb = 0; nb < 4; ++nb) s[mb][nb] = zero4;
#pragma unroll
    for (int kk = 0; kk < 2; ++kk) {
      half8 kf[4];
#pragma unroll
      for (int nb = 0; nb < 4; ++nb) {
        int row = nb * 16 + lr;
        int byo = (kk * 64 + lk * 16) ^ ((row & 7) << 4);
        kf[nb] = *reinterpret_cast<const half8*>(
            reinterpret_cast<const char*>(&Klds[row * 64]) + byo);
      }
#pragma unroll
      for (int mb = 0; mb < 2; ++mb)
#pragma unroll
        for (int nb = 0; nb < 4; ++nb)
          s[mb][nb] = __builtin_amdgcn_mfma_f32_16x16x32_f16(qf[mb][kk], kf[nb], s[mb][nb], 0, 0, 0);
    }

    // online softmax + P write (wave-private rows of Plds)
#pragma unroll
    for (int mb = 0; mb < 2; ++mb)
#pragma unroll
      for (int rg = 0; rg < 4; ++rg) {
        float tm = fmaxf(fmaxf(s[mb][0][rg], s[mb][1][rg]),
                         fmaxf(s[mb][2][rg], s[mb][3][rg]));
        tm = fmaxf(tm, __shfl_xor(tm, 1));
        tm = fmaxf(tm, __shfl_xor(tm, 2));
        tm = fmaxf(tm, __shfl_xor(tm, 4));
        tm = fmaxf(tm, __shfl_xor(tm, 8));
        float mo = m_r[mb][rg];
        float mn = fmaxf(mo, tm);
        float corr = __expf(mo - mn);
        float p0 = __expf(s[mb][0][rg] - mn);
        float p1 = __expf(s[mb][1][rg] - mn);
        float p2 = __expf(s[mb][2][rg] - mn);
        float p3 = __expf(s[mb][3][rg] - mn);
        float rs = p0 + p1 + p2 + p3;
        rs += __shfl_xor(rs, 1);
        rs += __shfl_xor(rs, 2);
        rs += __shfl_xor(rs, 4);
        rs += __shfl_xor(rs, 8);
        l_r[mb][rg] = l_r[mb][rg] * corr + rs;
        m_r[mb][rg] = mn;
#pragma unroll
        for (int nd = 0; nd < 4; ++nd) o[mb][nd][rg] *= corr;
        int q = w * 32 + mb * 16 + lk * 4 + rg;
        int fq = (q & 7) << 4;
        char* prow = reinterpret_cast<char*>(&Plds[q * 64]);
        *reinterpret_cast<f16*>(prow + (((lr + 0) * 2) ^ fq))  = (f16)p0;
        *reinterpret_cast<f16*>(prow + (((lr + 16) * 2) ^ fq)) = (f16)p1;
        *reinterpret_cast<f16*>(prow + (((lr + 32) * 2) ^ fq)) = (f16)p2;
        *reinterpret_cast<f16*>(prow + (((lr + 48) * 2) ^ fq)) = (f16)p3;
      }

    // O += P @ V
#pragma unroll
    for (int kk = 0; kk < 2; ++kk) {
      half8 pf[2], vf[4];
#pragma unroll
      for (int mb = 0; mb < 2; ++mb) {
        int row = w * 32 + mb * 16 + lr;
        int byo = (kk * 64 + lk * 16) ^ ((row & 7) << 4);
        pf[mb] = *reinterpret_cast<const half8*>(
            reinterpret_cast<const char*>(&Plds[row * 64]) + byo);
      }
#pragma unroll
      for (int nd = 0; nd < 4; ++nd) {
        int d = nd * 16 + lr;
        int f = (d & 7) ^ ((d >> 3) & 7);
        int byo = (kk * 64 + lk * 16) ^ (f << 4);
        vf[nd] = *reinterpret_cast<const half8*>(
            reinterpret_cast<const char*>(&Vlds[d * 64]) + byo);
      }
#pragma unroll
      for (int mb = 0; mb < 2; ++mb)
#pragma unroll
        for (int nd = 0; nd < 4; ++nd)
          o[mb][nd] = __builtin_amdgcn_mfma_f32_16x16x32_f16(pf[mb], vf[nd], o[mb][nd], 0, 0, 0);
    }
    __syncthreads();
  }

  // epilogue: normalize + store f16
#pragma unroll
  for (int mb = 0; mb < 2; ++mb)
#pragma unroll
    for (int rg = 0; rg < 4; ++rg) {
      int q = w * 32 + mb * 16 + lk * 4 + rg;
      float inv = 1.0f / l_r[mb][rg];
#pragma unroll
      for (int nd = 0; nd < 4; ++nd) {
        int d = nd * 16 + lr;
        Op[(size_t)q * DM + d] = (f16)(o[mb][nd][rg] * inv);
      }
    }
}

// ---------------- launch ----------------
extern "C" void kernel_launch(void* const* d_in, const int* in_sizes, int n_in,
                              void* d_out, int out_size, void* d_ws, size_t ws_size,
                              hipStream_t stream) {
  (void)in_sizes; (void)n_in; (void)out_size; (void)ws_size;
  const float* q  = (const float*)d_in[0];
  const float* k  = (const float*)d_in[1];
  const float* v  = (const float*)d_in[2];
  const float* Wq = (const float*)d_in[3];
  const float* bq = (const float*)d_in[4];
  const float* Wk = (const float*)d_in[5];
  const float* bk = (const float*)d_in[6];
  const float* Wv = (const float*)d_in[7];
  const float* bv = (const float*)d_in[8];
  const float* Wo = (const float*)d_in[9];
  const float* bo = (const float*)d_in[10];
  float* out = (float*)d_out;

  char* ws = (char*)d_ws;
  const size_t MB = 1u << 20;
  f16* qh  = (f16*)(ws + 0 * MB);
  f16* kh  = (f16*)(ws + 8 * MB);
  f16* vh  = (f16*)(ws + 16 * MB);
  f16* Wqh = (f16*)(ws + 24 * MB);
  f16* Wkh = (f16*)(ws + 26 * MB);
  f16* Wvh = (f16*)(ws + 28 * MB);
  f16* Woh = (f16*)(ws + 30 * MB);
  f16* Qp  = (f16*)(ws + 32 * MB);
  f16* Kp  = (f16*)(ws + 40 * MB);
  f16* Vp  = (f16*)(ws + 48 * MB);
  f16* At  = (f16*)(ws + 56 * MB);

  const int n8_in = (2 * SEQ * DM) / 8;   // 1,048,576... per-tensor: 4M/8
  cast_f2h<<<2048, 256, 0, stream>>>(q, qh, 4 * 1024 * 1024 / 8);
  cast_f2h<<<2048, 256, 0, stream>>>(k, kh, 4 * 1024 * 1024 / 8);
  cast_f2h<<<2048, 256, 0, stream>>>(v, vh, 4 * 1024 * 1024 / 8);
  cast_f2h<<<512, 256, 0, stream>>>(Wq, Wqh, 1024 * 1024 / 8);
  cast_f2h<<<512, 256, 0, stream>>>(Wk, Wkh, 1024 * 1024 / 8);
  cast_f2h<<<512, 256, 0, stream>>>(Wv, Wvh, 1024 * 1024 / 8);
  cast_f2h<<<512, 256, 0, stream>>>(Wo, Woh, 1024 * 1024 / 8);
  (void)n8_in;

  gemm_bt<1><<<dim3(8, 32, 3), 256, 0, stream>>>(qh, kh, vh, Wqh, Wkh, Wvh,
                                                 bq, bk, bv, Qp, Kp, Vp);
  attn_fwd<<<dim3(16, 32), 256, 0, stream>>>(Qp, Kp, Vp, At);
  gemm_bt<0><<<dim3(8, 32, 1), 256, 0, stream>>>(At, At, At, Woh, Woh, Woh,
                                                 bo, bo, bo, out, out, out);
}

// Round 3
// 156.018 us; speedup vs baseline: 1.6011x; 1.6011x over previous
//
#include <hip/hip_runtime.h>
#include <stdint.h>

#define DM   1024
#define SEQ  2048
#define NH   16
#define HD   64

typedef _Float16 f16;
typedef f16   half8 __attribute__((ext_vector_type(8)));
typedef f16   half4 __attribute__((ext_vector_type(4)));
typedef float f32x4 __attribute__((ext_vector_type(4)));
typedef float f32x16 __attribute__((ext_vector_type(16)));
typedef unsigned int u32;
typedef u32 u32x4 __attribute__((ext_vector_type(4)));

__device__ __forceinline__ void gl_lds16(const void* g, void* l) {
  __builtin_amdgcn_global_load_lds(
      reinterpret_cast<__attribute__((address_space(1))) u32*>(reinterpret_cast<uintptr_t>(g)),
      reinterpret_cast<__attribute__((address_space(3))) u32*>(reinterpret_cast<uintptr_t>(l)),
      16, 0, 0);
}

__device__ __forceinline__ u32 pkrtz(float a, float b) {
  auto h = __builtin_amdgcn_cvt_pkrtz(a, b);  // __fp16 x2
  return __builtin_bit_cast(u32, h);
}

// ---------------- cast f32 -> f16, 8 elems/thread ----------------
__global__ __launch_bounds__(256) void cast_f2h(const float* __restrict__ s,
                                                f16* __restrict__ d, int n8) {
  int i = blockIdx.x * 256 + threadIdx.x;
  if (i >= n8) return;
  const float4* s4 = reinterpret_cast<const float4*>(s);
  float4 a = s4[2 * (size_t)i];
  float4 b = s4[2 * (size_t)i + 1];
  half8 o;
  o[0] = (f16)a.x; o[1] = (f16)a.y; o[2] = (f16)a.z; o[3] = (f16)a.w;
  o[4] = (f16)b.x; o[5] = (f16)b.y; o[6] = (f16)b.z; o[7] = (f16)b.w;
  *reinterpret_cast<half8*>(d + 8 * (size_t)i) = o;
}

// ---------------- GEMM: C[M,N] = A[M,K] @ W[N,K]^T + bias, K=N=1024 ----------
template <int F16OUT>
__global__ __launch_bounds__(256) void gemm_bt(
    const f16* __restrict__ A0, const f16* __restrict__ A1, const f16* __restrict__ A2,
    const f16* __restrict__ W0, const f16* __restrict__ W1, const f16* __restrict__ W2,
    const float* __restrict__ b0, const float* __restrict__ b1, const float* __restrict__ b2,
    void* __restrict__ C0, void* __restrict__ C1, void* __restrict__ C2) {
  int z = blockIdx.z;
  const f16* A = (z == 0) ? A0 : (z == 1) ? A1 : A2;
  const f16* W = (z == 0) ? W0 : (z == 1) ? W1 : W2;
  const float* bias = (z == 0) ? b0 : (z == 1) ? b1 : b2;
  void* C = (z == 0) ? C0 : (z == 1) ? C1 : C2;

  __shared__ f16 As[128 * 32];
  __shared__ f16 Ws[128 * 32];

  int t = threadIdx.x;
  int w = t >> 6, lane = t & 63, lr = lane & 15, lk = lane >> 4;
  int m0 = blockIdx.y * 128, n0 = blockIdx.x * 128;
  int wr = (w >> 1) * 64, wc = (w & 1) * 64;

  int srow = t >> 2, scol = (t & 3) * 8;
  const f16* ga = A + (size_t)(m0 + srow) * DM + scol;
  const f16* gw = W + (size_t)(n0 + srow) * DM + scol;

  f32x4 zero4 = {0.f, 0.f, 0.f, 0.f};
  f32x4 acc[4][4];
#pragma unroll
  for (int mb = 0; mb < 4; ++mb)
#pragma unroll
    for (int nb = 0; nb < 4; ++nb) acc[mb][nb] = zero4;

  for (int k0 = 0; k0 < DM; k0 += 32) {
    gl_lds16(ga + k0,                   As + t * 8);
    gl_lds16(ga + k0 + (size_t)64 * DM, As + 2048 + t * 8);
    gl_lds16(gw + k0,                   Ws + t * 8);
    gl_lds16(gw + k0 + (size_t)64 * DM, Ws + 2048 + t * 8);
    __syncthreads();
    half8 af[4], wf[4];
#pragma unroll
    for (int mb = 0; mb < 4; ++mb)
      af[mb] = *reinterpret_cast<const half8*>(&As[(wr + mb * 16 + lr) * 32 + lk * 8]);
#pragma unroll
    for (int nb = 0; nb < 4; ++nb)
      wf[nb] = *reinterpret_cast<const half8*>(&Ws[(wc + nb * 16 + lr) * 32 + lk * 8]);
#pragma unroll
    for (int mb = 0; mb < 4; ++mb)
#pragma unroll
      for (int nb = 0; nb < 4; ++nb)
        acc[mb][nb] = __builtin_amdgcn_mfma_f32_16x16x32_f16(af[mb], wf[nb], acc[mb][nb], 0, 0, 0);
    __syncthreads();
  }

  float bv[4];
#pragma unroll
  for (int nb = 0; nb < 4; ++nb) bv[nb] = bias[n0 + wc + nb * 16 + lr];
#pragma unroll
  for (int mb = 0; mb < 4; ++mb)
#pragma unroll
    for (int nb = 0; nb < 4; ++nb)
#pragma unroll
      for (int j = 0; j < 4; ++j) {
        int r = m0 + wr + mb * 16 + lk * 4 + j;
        int c = n0 + wc + nb * 16 + lr;
        float v = acc[mb][nb][j] + bv[nb];
        if (F16OUT)
          ((f16*)C)[(size_t)r * DM + c] = (f16)v;
        else
          ((float*)C)[(size_t)r * DM + c] = v;
      }
}

// ---------------- flash attention fwd, swapped-operand 32x32x16 ----------------
// grid (16 qtiles, 32 b*h), 256 thr (4 waves x 32 q-rows). KVBLK=64.
// Per lane: owns q-row (lane&31); P kept fully in registers via swapped QK^T.
__global__ __launch_bounds__(256) void attn_fwd2(const f16* __restrict__ Qg,
                                                 const f16* __restrict__ Kg,
                                                 const f16* __restrict__ Vg,
                                                 f16* __restrict__ Og) {
  int qt = blockIdx.x;
  int bh = blockIdx.y;
  int b = bh >> 4, h = bh & 15;
  size_t base = (size_t)b * SEQ * DM + (size_t)h * HD;
  const f16* Kp = Kg + base;
  const f16* Vp = Vg + base;

  __shared__ f16 Kl[2][64 * 64];  // [kv][d], byte = kv*128 + (c ^ ((kv&7)<<4))
  __shared__ f16 Vt[2][64 * 64];  // [d][kv], byte = d*128 + (c ^ (((d&7)^((d>>3)&7))<<4))

  int t = threadIdx.x;
  int w = t >> 6, lane = t & 63;
  int l31 = lane & 31, lh = lane >> 5;
  int srow = t >> 3, scb = t & 7;

  // ---- Q fragments straight from global (held all kernel) ----
  int qrow = qt * 128 + w * 32 + l31;
  const f16* Qrow = Qg + base + (size_t)qrow * DM;
  half8 qf[4];
#pragma unroll
  for (int s = 0; s < 4; ++s)
    qf[s] = *reinterpret_cast<const half8*>(Qrow + s * 16 + lh * 8);

  auto stageK = [&](int kt, int buf) {
    const f16* Kt = Kp + (size_t)(kt * 64) * DM;
    int gc = (scb ^ (srow & 7)) * 8;
    gl_lds16(Kt + (size_t)srow * DM + gc,        &Kl[buf][t * 8]);
    gl_lds16(Kt + (size_t)(srow + 32) * DM + gc, &Kl[buf][2048 + t * 8]);
  };
  auto readKf = [&](int buf, int nbk, int s) -> half8 {
    int kv = nbk * 32 + l31;
    int c = (s * 32 + lh * 16) ^ ((kv & 7) << 4);
    return *reinterpret_cast<const half8*>(
        reinterpret_cast<const char*>(&Kl[buf][0]) + kv * 128 + c);
  };
  auto readVf = [&](int buf, int mb, int s2) -> half8 {
    int d = mb * 32 + l31;
    int f = (d & 7) ^ ((d >> 3) & 7);
    int c = (s2 * 32 + lh * 16) ^ (f << 4);
    return *reinterpret_cast<const half8*>(
        reinterpret_cast<const char*>(&Vt[buf][0]) + d * 128 + c);
  };
  auto loadV = [&](int kt, half8& v0, half8& v1) {
    const f16* Vtile = Vp + (size_t)(kt * 64) * DM;
    v0 = *reinterpret_cast<const half8*>(Vtile + (size_t)srow * DM + scb * 8);
    v1 = *reinterpret_cast<const half8*>(Vtile + (size_t)(srow + 32) * DM + scb * 8);
  };
  auto writeVt = [&](int buf, half8 v0, half8 v1) {
#pragma unroll
    for (int i = 0; i < 2; ++i) {
      int kv = i * 32 + srow;
      half8 vv = i ? v1 : v0;
#pragma unroll
      for (int j = 0; j < 8; ++j) {
        int d = scb * 8 + j;
        int f = (d & 7) ^ ((d >> 3) & 7);
        int byo = (kv * 2) ^ (f << 4);
        *reinterpret_cast<f16*>(reinterpret_cast<char*>(&Vt[buf][0]) + d * 128 + byo) = vv[j];
      }
    }
  };

  f32x16 o0, o1;
#pragma unroll
  for (int i = 0; i < 16; ++i) { o0[i] = 0.f; o1[i] = 0.f; }
  float m_r = -1e30f, l_r = 0.f;

  half8 vn0, vn1;
  stageK(0, 0);
  loadV(0, vn0, vn1);
  writeVt(0, vn0, vn1);
  __syncthreads();

  const int NT = SEQ / 64;
  for (int kt = 0; kt < NT; ++kt) {
    int cur = kt & 1;
    bool pre = (kt + 1 < NT);
    if (pre) { stageK(kt + 1, cur ^ 1); loadV(kt + 1, vn0, vn1); }

    // ---- S^T = K @ Q^T : lane owns q = l31; regs span kv ----
    f32x16 s0, s1;
#pragma unroll
    for (int i = 0; i < 16; ++i) { s0[i] = 0.f; s1[i] = 0.f; }
#pragma unroll
    for (int s = 0; s < 4; ++s) {
      half8 k0 = readKf(cur, 0, s);
      half8 k1 = readKf(cur, 1, s);
      s0 = __builtin_amdgcn_mfma_f32_32x32x16_f16(k0, qf[s], s0, 0, 0, 0);
      s1 = __builtin_amdgcn_mfma_f32_32x32x16_f16(k1, qf[s], s1, 0, 0, 0);
    }

    // ---- online softmax (in-register; 1 cross-lane op per reduce) ----
    float tm[8];
#pragma unroll
    for (int i = 0; i < 8; ++i)
      tm[i] = fmaxf(fmaxf(s0[i], s0[i + 8]), fmaxf(s1[i], s1[i + 8]));
#pragma unroll
    for (int i = 0; i < 4; ++i) tm[i] = fmaxf(tm[i], tm[i + 4]);
    float mx = fmaxf(fmaxf(tm[0], tm[1]), fmaxf(tm[2], tm[3]));
    mx = fmaxf(mx, __shfl_xor(mx, 32));

    if (__any(mx > m_r + 8.f)) {  // defer-max (T13)
      float mn = fmaxf(m_r, mx);
      float corr = __expf(m_r - mn);
      m_r = mn;
      l_r *= corr;
#pragma unroll
      for (int i = 0; i < 16; ++i) { o0[i] *= corr; o1[i] *= corr; }
    }
    float rs0 = 0.f, rs1 = 0.f;
#pragma unroll
    for (int i = 0; i < 16; ++i) { s0[i] = __expf(s0[i] - m_r); rs0 += s0[i]; }
#pragma unroll
    for (int i = 0; i < 16; ++i) { s1[i] = __expf(s1[i] - m_r); rs1 += s1[i]; }
    float rs = rs0 + rs1;
    rs += __shfl_xor(rs, 32);
    l_r += rs;

    // ---- pack P -> f16 frags (cvt_pkrtz + permlane32_swap), then PV ----
#pragma unroll
    for (int nb = 0; nb < 2; ++nb) {
      const f32x16& sp = nb ? s1 : s0;
      u32 u0 = pkrtz(sp[0], sp[1]);
      u32 u1 = pkrtz(sp[2], sp[3]);
      u32 u2 = pkrtz(sp[4], sp[5]);
      u32 u3 = pkrtz(sp[6], sp[7]);
      u32 u4 = pkrtz(sp[8], sp[9]);
      u32 u5 = pkrtz(sp[10], sp[11]);
      u32 u6 = pkrtz(sp[12], sp[13]);
      u32 u7 = pkrtz(sp[14], sp[15]);
      asm volatile("v_permlane32_swap_b32 %0, %1" : "+v"(u0), "+v"(u2));
      asm volatile("v_permlane32_swap_b32 %0, %1" : "+v"(u1), "+v"(u3));
      asm volatile("v_permlane32_swap_b32 %0, %1" : "+v"(u4), "+v"(u6));
      asm volatile("v_permlane32_swap_b32 %0, %1" : "+v"(u5), "+v"(u7));
      u32x4 w0 = {u0, u1, u2, u3};
      u32x4 w1 = {u4, u5, u6, u7};
      half8 pa0 = __builtin_bit_cast(half8, w0);
      half8 pa1 = __builtin_bit_cast(half8, w1);
      half8 va, vb;
      va = readVf(cur, 0, 2 * nb);
      vb = readVf(cur, 1, 2 * nb);
      o0 = __builtin_amdgcn_mfma_f32_32x32x16_f16(va, pa0, o0, 0, 0, 0);
      o1 = __builtin_amdgcn_mfma_f32_32x32x16_f16(vb, pa0, o1, 0, 0, 0);
      va = readVf(cur, 0, 2 * nb + 1);
      vb = readVf(cur, 1, 2 * nb + 1);
      o0 = __builtin_amdgcn_mfma_f32_32x32x16_f16(va, pa1, o0, 0, 0, 0);
      o1 = __builtin_amdgcn_mfma_f32_32x32x16_f16(vb, pa1, o1, 0, 0, 0);
    }

    __syncthreads();
    if (pre) writeVt(cur ^ 1, vn0, vn1);
    __syncthreads();
  }

  // ---- epilogue: normalize + store f16 (RNE casts) ----
  float inv = 1.0f / l_r;
  f16* Orow = Og + base + (size_t)qrow * DM;
#pragma unroll
  for (int mb = 0; mb < 2; ++mb) {
    const f32x16& oo = mb ? o1 : o0;
#pragma unroll
    for (int rq = 0; rq < 4; ++rq) {
      half4 hv;
      hv[0] = (f16)(oo[4 * rq + 0] * inv);
      hv[1] = (f16)(oo[4 * rq + 1] * inv);
      hv[2] = (f16)(oo[4 * rq + 2] * inv);
      hv[3] = (f16)(oo[4 * rq + 3] * inv);
      *reinterpret_cast<half4*>(Orow + mb * 32 + 8 * rq + 4 * lh) = hv;
    }
  }
}

// ---------------- launch ----------------
extern "C" void kernel_launch(void* const* d_in, const int* in_sizes, int n_in,
                              void* d_out, int out_size, void* d_ws, size_t ws_size,
                              hipStream_t stream) {
  (void)in_sizes; (void)n_in; (void)out_size; (void)ws_size;
  const float* q  = (const float*)d_in[0];
  const float* k  = (const float*)d_in[1];
  const float* v  = (const float*)d_in[2];
  const float* Wq = (const float*)d_in[3];
  const float* bq = (const float*)d_in[4];
  const float* Wk = (const float*)d_in[5];
  const float* bk = (const float*)d_in[6];
  const float* Wv = (const float*)d_in[7];
  const float* bv = (const float*)d_in[8];
  const float* Wo = (const float*)d_in[9];
  const float* bo = (const float*)d_in[10];
  float* out = (float*)d_out;

  char* ws = (char*)d_ws;
  const size_t MB = 1u << 20;
  f16* qh  = (f16*)(ws + 0 * MB);
  f16* kh  = (f16*)(ws + 8 * MB);
  f16* vh  = (f16*)(ws + 16 * MB);
  f16* Wqh = (f16*)(ws + 24 * MB);
  f16* Wkh = (f16*)(ws + 26 * MB);
  f16* Wvh = (f16*)(ws + 28 * MB);
  f16* Woh = (f16*)(ws + 30 * MB);
  f16* Qp  = (f16*)(ws + 32 * MB);
  f16* Kp  = (f16*)(ws + 40 * MB);
  f16* Vp  = (f16*)(ws + 48 * MB);
  f16* At  = (f16*)(ws + 56 * MB);

  cast_f2h<<<2048, 256, 0, stream>>>(q, qh, 4 * 1024 * 1024 / 8);
  cast_f2h<<<2048, 256, 0, stream>>>(k, kh, 4 * 1024 * 1024 / 8);
  cast_f2h<<<2048, 256, 0, stream>>>(v, vh, 4 * 1024 * 1024 / 8);
  cast_f2h<<<512, 256, 0, stream>>>(Wq, Wqh, 1024 * 1024 / 8);
  cast_f2h<<<512, 256, 0, stream>>>(Wk, Wkh, 1024 * 1024 / 8);
  cast_f2h<<<512, 256, 0, stream>>>(Wv, Wvh, 1024 * 1024 / 8);
  cast_f2h<<<512, 256, 0, stream>>>(Wo, Woh, 1024 * 1024 / 8);

  gemm_bt<1><<<dim3(8, 32, 3), 256, 0, stream>>>(qh, kh, vh, Wqh, Wkh, Wvh,
                                                 bq, bk, bv, Qp, Kp, Vp);
  attn_fwd2<<<dim3(16, 32), 256, 0, stream>>>(Qp, Kp, Vp, At);
  gemm_bt<0><<<dim3(8, 32, 1), 256, 0, stream>>>(At, At, At, Woh, Woh, Woh,
                                                 bo, bo, bo, out, out, out);
}

// Round 4
// 151.696 us; speedup vs baseline: 1.6467x; 1.0285x over previous
//
#include <hip/hip_runtime.h>
#include <stdint.h>

#define DM   1024
#define SEQ  2048
#define NH   16
#define HD   64

typedef _Float16 f16;
typedef f16   half8 __attribute__((ext_vector_type(8)));
typedef f16   half4 __attribute__((ext_vector_type(4)));
typedef float f32x4 __attribute__((ext_vector_type(4)));
typedef float f32x16 __attribute__((ext_vector_type(16)));
typedef unsigned int u32;
typedef u32 u32x4 __attribute__((ext_vector_type(4)));

__device__ __forceinline__ void gl_lds16(const void* g, void* l) {
  __builtin_amdgcn_global_load_lds(
      reinterpret_cast<__attribute__((address_space(1))) u32*>(reinterpret_cast<uintptr_t>(g)),
      reinterpret_cast<__attribute__((address_space(3))) u32*>(reinterpret_cast<uintptr_t>(l)),
      16, 0, 0);
}

__device__ __forceinline__ u32 pkrtz(float a, float b) {
  auto h = __builtin_amdgcn_cvt_pkrtz(a, b);  // __fp16 x2
  return __builtin_bit_cast(u32, h);
}

// ---------------- fused cast f32 -> f16 (all 7 tensors, one launch) ----------
__global__ __launch_bounds__(256) void cast_all(
    const float* __restrict__ q, const float* __restrict__ k, const float* __restrict__ v,
    const float* __restrict__ Wq, const float* __restrict__ Wk,
    const float* __restrict__ Wv, const float* __restrict__ Wo,
    f16* __restrict__ qh, f16* __restrict__ kh, f16* __restrict__ vh,
    f16* __restrict__ Wqh, f16* __restrict__ Wkh, f16* __restrict__ Wvh,
    f16* __restrict__ Woh) {
  int i = blockIdx.x * 256 + threadIdx.x;  // 8-elem group id; total 2097152
  const float* s;
  f16* d;
  int off;
  if (i < 1572864) {
    int sel = i >> 19;       // / 524288
    off = i & 524287;
    s = sel == 0 ? q : sel == 1 ? k : v;
    d = sel == 0 ? qh : sel == 1 ? kh : vh;
  } else {
    int j = i - 1572864;
    int sel = j >> 17;       // / 131072
    off = j & 131071;
    s = sel == 0 ? Wq : sel == 1 ? Wk : sel == 2 ? Wv : Wo;
    d = sel == 0 ? Wqh : sel == 1 ? Wkh : sel == 2 ? Wvh : Woh;
  }
  const float4* s4 = reinterpret_cast<const float4*>(s);
  float4 a = s4[2 * (size_t)off];
  float4 b = s4[2 * (size_t)off + 1];
  half8 o;
  o[0] = (f16)a.x; o[1] = (f16)a.y; o[2] = (f16)a.z; o[3] = (f16)a.w;
  o[4] = (f16)b.x; o[5] = (f16)b.y; o[6] = (f16)b.z; o[7] = (f16)b.w;
  *reinterpret_cast<half8*>(d + 8 * (size_t)off) = o;
}

// ---------------- QKV GEMM: C[M,N] = A[M,K] @ W[N,K]^T + bias ----------------
// z=0: Q normal f16 [b][s][dm]; z=1: K normal; z=2: V transposed [b][h][d][s].
__global__ __launch_bounds__(256) void gemm_qkv(
    const f16* __restrict__ A0, const f16* __restrict__ A1, const f16* __restrict__ A2,
    const f16* __restrict__ W0, const f16* __restrict__ W1, const f16* __restrict__ W2,
    const float* __restrict__ b0, const float* __restrict__ b1, const float* __restrict__ b2,
    f16* __restrict__ C0, f16* __restrict__ C1, f16* __restrict__ C2) {
  int z = blockIdx.z;
  const f16* A = (z == 0) ? A0 : (z == 1) ? A1 : A2;
  const f16* W = (z == 0) ? W0 : (z == 1) ? W1 : W2;
  const float* bias = (z == 0) ? b0 : (z == 1) ? b1 : b2;

  __shared__ f16 As[128 * 32];
  __shared__ f16 Ws[128 * 32];

  int t = threadIdx.x;
  int w = t >> 6, lane = t & 63, lr = lane & 15, lk = lane >> 4;
  int m0 = blockIdx.y * 128, n0 = blockIdx.x * 128;
  int wr = (w >> 1) * 64, wc = (w & 1) * 64;

  int srow = t >> 2, scol = (t & 3) * 8;
  const f16* ga = A + (size_t)(m0 + srow) * DM + scol;
  const f16* gw = W + (size_t)(n0 + srow) * DM + scol;

  f32x4 zero4 = {0.f, 0.f, 0.f, 0.f};
  f32x4 acc[4][4];
#pragma unroll
  for (int mb = 0; mb < 4; ++mb)
#pragma unroll
    for (int nb = 0; nb < 4; ++nb) acc[mb][nb] = zero4;

  for (int k0 = 0; k0 < DM; k0 += 32) {
    gl_lds16(ga + k0,                   As + t * 8);
    gl_lds16(ga + k0 + (size_t)64 * DM, As + 2048 + t * 8);
    gl_lds16(gw + k0,                   Ws + t * 8);
    gl_lds16(gw + k0 + (size_t)64 * DM, Ws + 2048 + t * 8);
    __syncthreads();
    half8 af[4], wf[4];
#pragma unroll
    for (int mb = 0; mb < 4; ++mb)
      af[mb] = *reinterpret_cast<const half8*>(&As[(wr + mb * 16 + lr) * 32 + lk * 8]);
#pragma unroll
    for (int nb = 0; nb < 4; ++nb)
      wf[nb] = *reinterpret_cast<const half8*>(&Ws[(wc + nb * 16 + lr) * 32 + lk * 8]);
#pragma unroll
    for (int mb = 0; mb < 4; ++mb)
#pragma unroll
      for (int nb = 0; nb < 4; ++nb)
        acc[mb][nb] = __builtin_amdgcn_mfma_f32_16x16x32_f16(af[mb], wf[nb], acc[mb][nb], 0, 0, 0);
    __syncthreads();
  }

  float bv[4];
#pragma unroll
  for (int nb = 0; nb < 4; ++nb) bv[nb] = bias[n0 + wc + nb * 16 + lr];

  if (z == 2) {
    // V^T per-head: Vt[((b*NH+h)*HD + d)*SEQ + s], s = global row, contiguous j
#pragma unroll
    for (int mb = 0; mb < 4; ++mb)
#pragma unroll
      for (int nb = 0; nb < 4; ++nb) {
        int r0 = m0 + wr + mb * 16 + lk * 4;
        int c = n0 + wc + nb * 16 + lr;
        int b_ = r0 >> 11, s_ = r0 & 2047;
        int h_ = c >> 6, d_ = c & 63;
        f16* dst = C2 + (((size_t)(b_ * NH + h_) * HD + d_) * SEQ + s_);
        half4 hv;
#pragma unroll
        for (int j = 0; j < 4; ++j) hv[j] = (f16)(acc[mb][nb][j] + bv[nb]);
        *reinterpret_cast<half4*>(dst) = hv;
      }
  } else {
    f16* C = (z == 0) ? C0 : C1;
#pragma unroll
    for (int mb = 0; mb < 4; ++mb)
#pragma unroll
      for (int nb = 0; nb < 4; ++nb)
#pragma unroll
        for (int j = 0; j < 4; ++j) {
          int r = m0 + wr + mb * 16 + lk * 4 + j;
          int c = n0 + wc + nb * 16 + lr;
          C[(size_t)r * DM + c] = (f16)(acc[mb][nb][j] + bv[nb]);
        }
  }
}

// ---------------- output projection GEMM (f32 out) ----------------
__global__ __launch_bounds__(256) void gemm_out(
    const f16* __restrict__ A, const f16* __restrict__ W,
    const float* __restrict__ bias, float* __restrict__ C) {
  __shared__ f16 As[128 * 32];
  __shared__ f16 Ws[128 * 32];

  int t = threadIdx.x;
  int w = t >> 6, lane = t & 63, lr = lane & 15, lk = lane >> 4;
  int m0 = blockIdx.y * 128, n0 = blockIdx.x * 128;
  int wr = (w >> 1) * 64, wc = (w & 1) * 64;

  int srow = t >> 2, scol = (t & 3) * 8;
  const f16* ga = A + (size_t)(m0 + srow) * DM + scol;
  const f16* gw = W + (size_t)(n0 + srow) * DM + scol;

  f32x4 zero4 = {0.f, 0.f, 0.f, 0.f};
  f32x4 acc[4][4];
#pragma unroll
  for (int mb = 0; mb < 4; ++mb)
#pragma unroll
    for (int nb = 0; nb < 4; ++nb) acc[mb][nb] = zero4;

  for (int k0 = 0; k0 < DM; k0 += 32) {
    gl_lds16(ga + k0,                   As + t * 8);
    gl_lds16(ga + k0 + (size_t)64 * DM, As + 2048 + t * 8);
    gl_lds16(gw + k0,                   Ws + t * 8);
    gl_lds16(gw + k0 + (size_t)64 * DM, Ws + 2048 + t * 8);
    __syncthreads();
    half8 af[4], wf[4];
#pragma unroll
    for (int mb = 0; mb < 4; ++mb)
      af[mb] = *reinterpret_cast<const half8*>(&As[(wr + mb * 16 + lr) * 32 + lk * 8]);
#pragma unroll
    for (int nb = 0; nb < 4; ++nb)
      wf[nb] = *reinterpret_cast<const half8*>(&Ws[(wc + nb * 16 + lr) * 32 + lk * 8]);
#pragma unroll
    for (int mb = 0; mb < 4; ++mb)
#pragma unroll
      for (int nb = 0; nb < 4; ++nb)
        acc[mb][nb] = __builtin_amdgcn_mfma_f32_16x16x32_f16(af[mb], wf[nb], acc[mb][nb], 0, 0, 0);
    __syncthreads();
  }

  float bv[4];
#pragma unroll
  for (int nb = 0; nb < 4; ++nb) bv[nb] = bias[n0 + wc + nb * 16 + lr];
#pragma unroll
  for (int mb = 0; mb < 4; ++mb)
#pragma unroll
    for (int nb = 0; nb < 4; ++nb)
#pragma unroll
      for (int j = 0; j < 4; ++j) {
        int r = m0 + wr + mb * 16 + lk * 4 + j;
        int c = n0 + wc + nb * 16 + lr;
        C[(size_t)r * DM + c] = acc[mb][nb][j] + bv[nb];
      }
}

// ---------------- flash attention fwd ----------------
// grid (32 qtiles, 32 b*h), 128 thr (2 waves x 32 q-rows). KVBLK=64.
// K and V^T both staged linearly via global_load_lds (swizzled source);
// single barrier per tile; P fully in registers (swapped QK^T).
__global__ __launch_bounds__(128, 2) void attn_fwd3(const f16* __restrict__ Qg,
                                                    const f16* __restrict__ Kg,
                                                    const f16* __restrict__ VTg,
                                                    f16* __restrict__ Og) {
  int qt = blockIdx.x;
  int bh = blockIdx.y;
  int b = bh >> 4, h = bh & 15;
  size_t baseq = (size_t)b * SEQ * DM + (size_t)h * HD;
  const f16* Kp = Kg + baseq;
  const f16* VTp = VTg + (size_t)bh * HD * SEQ;  // [d][s]

  __shared__ f16 Kl[2][64 * 64];  // [kv][d], byte = kv*128 + (c ^ ((kv&7)<<4))
  __shared__ f16 Vl[2][64 * 64];  // [d][kv], byte = d*128 + (c ^ ((d&7)<<4))

  int t = threadIdx.x;
  int w = t >> 6, lane = t & 63;
  int l31 = lane & 31, lh = lane >> 5;
  int srow = t >> 3, scb = t & 7;  // srow 0..15

  // ---- Q fragments straight from global (held all kernel) ----
  int qrow = qt * 64 + w * 32 + l31;
  const f16* Qrow = Qg + baseq + (size_t)qrow * DM;
  half8 qf[4];
#pragma unroll
  for (int s = 0; s < 4; ++s)
    qf[s] = *reinterpret_cast<const half8*>(Qrow + s * 16 + lh * 8);

  auto stage = [&](int kt, int buf) {
    const f16* Kt = Kp + (size_t)(kt * 64) * DM;
    const f16* Vt = VTp + kt * 64;
#pragma unroll
    for (int i = 0; i < 4; ++i) {
      int row = i * 16 + srow;
      int gc = (scb ^ (row & 7)) * 8;
      gl_lds16(Kt + (size_t)row * DM + gc, &Kl[buf][row * 64 + scb * 8]);
    }
#pragma unroll
    for (int i = 0; i < 4; ++i) {
      int d = i * 16 + srow;
      int gc = (scb ^ (d & 7)) * 8;
      gl_lds16(Vt + (size_t)d * SEQ + gc, &Vl[buf][d * 64 + scb * 8]);
    }
  };
  auto readKf = [&](int buf, int nbk, int s) -> half8 {
    int kv = nbk * 32 + l31;
    int c = (s * 32 + lh * 16) ^ ((kv & 7) << 4);
    return *reinterpret_cast<const half8*>(
        reinterpret_cast<const char*>(&Kl[buf][0]) + kv * 128 + c);
  };
  auto readVf = [&](int buf, int mb, int s2) -> half8 {
    int d = mb * 32 + l31;
    int c = (s2 * 32 + lh * 16) ^ ((d & 7) << 4);
    return *reinterpret_cast<const half8*>(
        reinterpret_cast<const char*>(&Vl[buf][0]) + d * 128 + c);
  };

  f32x16 o0, o1;
#pragma unroll
  for (int i = 0; i < 16; ++i) { o0[i] = 0.f; o1[i] = 0.f; }
  float m_r = -1e30f, l_r = 0.f;

  stage(0, 0);
  __syncthreads();

  const int NT = SEQ / 64;
  for (int kt = 0; kt < NT; ++kt) {
    int cur = kt & 1;
    if (kt + 1 < NT) stage(kt + 1, cur ^ 1);

    // ---- S^T = K @ Q^T : lane owns q = l31; regs span kv ----
    f32x16 s0, s1;
#pragma unroll
    for (int i = 0; i < 16; ++i) { s0[i] = 0.f; s1[i] = 0.f; }
    __builtin_amdgcn_s_setprio(1);
#pragma unroll
    for (int s = 0; s < 4; ++s) {
      half8 k0 = readKf(cur, 0, s);
      half8 k1 = readKf(cur, 1, s);
      s0 = __builtin_amdgcn_mfma_f32_32x32x16_f16(k0, qf[s], s0, 0, 0, 0);
      s1 = __builtin_amdgcn_mfma_f32_32x32x16_f16(k1, qf[s], s1, 0, 0, 0);
    }
    __builtin_amdgcn_s_setprio(0);

    // ---- online softmax (in-register; 1 cross-lane op per reduce) ----
    float tm[8];
#pragma unroll
    for (int i = 0; i < 8; ++i)
      tm[i] = fmaxf(fmaxf(s0[i], s0[i + 8]), fmaxf(s1[i], s1[i + 8]));
#pragma unroll
    for (int i = 0; i < 4; ++i) tm[i] = fmaxf(tm[i], tm[i + 4]);
    float mx = fmaxf(fmaxf(tm[0], tm[1]), fmaxf(tm[2], tm[3]));
    mx = fmaxf(mx, __shfl_xor(mx, 32));

    if (__any(mx > m_r + 8.f)) {  // defer-max (T13)
      float mn = fmaxf(m_r, mx);
      float corr = __expf(m_r - mn);
      m_r = mn;
      l_r *= corr;
#pragma unroll
      for (int i = 0; i < 16; ++i) { o0[i] *= corr; o1[i] *= corr; }
    }
    float rs0 = 0.f, rs1 = 0.f;
#pragma unroll
    for (int i = 0; i < 16; ++i) { s0[i] = __expf(s0[i] - m_r); rs0 += s0[i]; }
#pragma unroll
    for (int i = 0; i < 16; ++i) { s1[i] = __expf(s1[i] - m_r); rs1 += s1[i]; }
    float rs = rs0 + rs1;
    rs += __shfl_xor(rs, 32);
    l_r += rs;

    // ---- pack P -> f16 frags (cvt_pkrtz + permlane32_swap), then PV ----
#pragma unroll
    for (int nb = 0; nb < 2; ++nb) {
      const f32x16& sp = nb ? s1 : s0;
      u32 u0 = pkrtz(sp[0], sp[1]);
      u32 u1 = pkrtz(sp[2], sp[3]);
      u32 u2 = pkrtz(sp[4], sp[5]);
      u32 u3 = pkrtz(sp[6], sp[7]);
      u32 u4 = pkrtz(sp[8], sp[9]);
      u32 u5 = pkrtz(sp[10], sp[11]);
      u32 u6 = pkrtz(sp[12], sp[13]);
      u32 u7 = pkrtz(sp[14], sp[15]);
      asm volatile("v_permlane32_swap_b32 %0, %1" : "+v"(u0), "+v"(u2));
      asm volatile("v_permlane32_swap_b32 %0, %1" : "+v"(u1), "+v"(u3));
      asm volatile("v_permlane32_swap_b32 %0, %1" : "+v"(u4), "+v"(u6));
      asm volatile("v_permlane32_swap_b32 %0, %1" : "+v"(u5), "+v"(u7));
      u32x4 w0 = {u0, u1, u2, u3};
      u32x4 w1 = {u4, u5, u6, u7};
      half8 pa0 = __builtin_bit_cast(half8, w0);
      half8 pa1 = __builtin_bit_cast(half8, w1);
      half8 va, vb;
      va = readVf(cur, 0, 2 * nb);
      vb = readVf(cur, 1, 2 * nb);
      __builtin_amdgcn_s_setprio(1);
      o0 = __builtin_amdgcn_mfma_f32_32x32x16_f16(va, pa0, o0, 0, 0, 0);
      o1 = __builtin_amdgcn_mfma_f32_32x32x16_f16(vb, pa0, o1, 0, 0, 0);
      __builtin_amdgcn_s_setprio(0);
      va = readVf(cur, 0, 2 * nb + 1);
      vb = readVf(cur, 1, 2 * nb + 1);
      __builtin_amdgcn_s_setprio(1);
      o0 = __builtin_amdgcn_mfma_f32_32x32x16_f16(va, pa1, o0, 0, 0, 0);
      o1 = __builtin_amdgcn_mfma_f32_32x32x16_f16(vb, pa1, o1, 0, 0, 0);
      __builtin_amdgcn_s_setprio(0);
    }

    __syncthreads();
  }

  // ---- epilogue: normalize + store f16 ----
  float inv = 1.0f / l_r;
  f16* Orow = Og + baseq + (size_t)qrow * DM;
#pragma unroll
  for (int mb = 0; mb < 2; ++mb) {
    const f32x16& oo = mb ? o1 : o0;
#pragma unroll
    for (int rq = 0; rq < 4; ++rq) {
      half4 hv;
      hv[0] = (f16)(oo[4 * rq + 0] * inv);
      hv[1] = (f16)(oo[4 * rq + 1] * inv);
      hv[2] = (f16)(oo[4 * rq + 2] * inv);
      hv[3] = (f16)(oo[4 * rq + 3] * inv);
      *reinterpret_cast<half4*>(Orow + mb * 32 + 8 * rq + 4 * lh) = hv;
    }
  }
}

// ---------------- launch ----------------
extern "C" void kernel_launch(void* const* d_in, const int* in_sizes, int n_in,
                              void* d_out, int out_size, void* d_ws, size_t ws_size,
                              hipStream_t stream) {
  (void)in_sizes; (void)n_in; (void)out_size; (void)ws_size;
  const float* q  = (const float*)d_in[0];
  const float* k  = (const float*)d_in[1];
  const float* v  = (const float*)d_in[2];
  const float* Wq = (const float*)d_in[3];
  const float* bq = (const float*)d_in[4];
  const float* Wk = (const float*)d_in[5];
  const float* bk = (const float*)d_in[6];
  const float* Wv = (const float*)d_in[7];
  const float* bv = (const float*)d_in[8];
  const float* Wo = (const float*)d_in[9];
  const float* bo = (const float*)d_in[10];
  float* out = (float*)d_out;

  char* ws = (char*)d_ws;
  const size_t MB = 1u << 20;
  f16* qh  = (f16*)(ws + 0 * MB);
  f16* kh  = (f16*)(ws + 8 * MB);
  f16* vh  = (f16*)(ws + 16 * MB);
  f16* Wqh = (f16*)(ws + 24 * MB);
  f16* Wkh = (f16*)(ws + 26 * MB);
  f16* Wvh = (f16*)(ws + 28 * MB);
  f16* Woh = (f16*)(ws + 30 * MB);
  f16* Qp  = (f16*)(ws + 32 * MB);
  f16* Kp  = (f16*)(ws + 40 * MB);
  f16* Vtp = (f16*)(ws + 48 * MB);  // [b][h][d][s]
  f16* At  = (f16*)(ws + 56 * MB);

  cast_all<<<8192, 256, 0, stream>>>(q, k, v, Wq, Wk, Wv, Wo,
                                     qh, kh, vh, Wqh, Wkh, Wvh, Woh);
  gemm_qkv<<<dim3(8, 32, 3), 256, 0, stream>>>(qh, kh, vh, Wqh, Wkh, Wvh,
                                               bq, bk, bv, Qp, Kp, Vtp);
  attn_fwd3<<<dim3(32, 32), 128, 0, stream>>>(Qp, Kp, Vtp, At);
  gemm_out<<<dim3(8, 32), 256, 0, stream>>>(At, Woh, bo, out);
}